// Round 4
// baseline (66.326 us; speedup 1.0000x reference)
//
#include <hip/hip_runtime.h>
#include <math.h>

// Problem constants (from reference setup_inputs)
#define BATCH 64
#define CHN   512
#define HW    1024          // 32*32 spatial
#define HEADS 16            // CHN / DIM_PERHEAD
#define DPH   32            // DIM_PERHEAD

// Native clang vector type: required by __builtin_nontemporal_store
// (HIP's float4 is a class and is rejected).
typedef float fvec4 __attribute__((ext_vector_type(4)));

// One block per (batch, head). 1024 threads: 32 threads per channel,
// strided float4s so each vector load instruction is coalesced.
// ot1 is prefetched BEFORE the reduction barrier so its HBM latency is
// hidden under the shuffle-reduce + barrier; post-barrier is pure FMA+store.
__global__ __launch_bounds__(1024) void mrla_fused_kernel(
    const float* __restrict__ xt,
    const float* __restrict__ ot1,
    const float* __restrict__ conv_w,
    const float* __restrict__ wv_w,
    const float* __restrict__ lambda_t,
    float* __restrict__ out)
{
    const int headi = blockIdx.x;       // 0..15
    const int b     = blockIdx.y;       // 0..63
    const int c0    = headi * DPH;      // first channel of this head
    const int t     = (int)threadIdx.x; // 0..1023
    const int ch    = t >> 5;           // channel within head, 0..31
    const int l     = t & 31;           // lane within channel group

    __shared__ float poolS[DPH + 2];    // pool sums for channels c0-1 .. c0+32
    __shared__ float attnS;

    const size_t base = ((size_t)b * CHN + c0) * (size_t)HW;  // xt[b][c0][0][0]
    const fvec4* xt4 = (const fvec4*)(xt + base);
    const fvec4* o4  = (const fvec4*)(ot1 + base);
    const int ch4 = ch * (HW / 4);      // this channel's float4 offset

    // ---- Phase 1: issue ALL global loads (xt tile + ot1 tile) ----
    fvec4 xr[8];
    fvec4 orr[8];
    #pragma unroll
    for (int j = 0; j < 8; ++j)
        xr[j] = xt4[ch4 + l + j * 32];
    #pragma unroll
    for (int j = 0; j < 8; ++j)
        orr[j] = o4[ch4 + l + j * 32];   // stays outstanding through reduce+barrier

    // per-channel pool sum over xt (waits only the xt loads)
    float s = 0.0f;
    #pragma unroll
    for (int j = 0; j < 8; ++j)
        s += xr[j].x + xr[j].y + xr[j].z + xr[j].w;
    // reduce across the 32 lanes sharing a channel (masks <32 stay in-half)
    #pragma unroll
    for (int m = 16; m >= 1; m >>= 1)
        s += __shfl_xor(s, m);
    if (l == 0) poolS[1 + ch] = s;

    // ---- Phase 1b: boundary channels (c0-1 by wave 0, c0+32 by wave 1) ----
    const int wv = t >> 6;
    if (wv < 2) {
        const int lane = t & 63;
        const int gc = (wv == 0) ? (c0 - 1) : (c0 + DPH);
        float bs = 0.0f;
        if (gc >= 0 && gc < CHN) {
            const fvec4* p4 = (const fvec4*)(xt + ((size_t)b * CHN + gc) * (size_t)HW);
            #pragma unroll
            for (int j = 0; j < 4; ++j) {
                fvec4 v = p4[lane + j * 64];
                bs += v.x + v.y + v.z + v.w;
            }
        }
        #pragma unroll
        for (int m = 32; m >= 1; m >>= 1)
            bs += __shfl_xor(bs, m);
        if (lane == 0) poolS[(wv == 0) ? 0 : (DPH + 1)] = bs;  // 0 if out of range
    }
    __syncthreads();

    // ---- Phase 2: conv1d(k=3) over channel means, head attention scalar ----
    if (t < DPH) {
        const float inv = 1.0f / (float)HW;
        const float w0 = conv_w[0], w1 = conv_w[1], w2 = conv_w[2];
        float y = (w0 * poolS[t] + w1 * poolS[t + 1] + w2 * poolS[t + 2]) * inv;
        float q = y * y;
        #pragma unroll
        for (int m = 16; m >= 1; m >>= 1)
            q += __shfl_xor(q, m);
        if (t == 0) {
            const float a = q * 0.17677669529663687f;   // / sqrt(32)
            attnS = 1.0f / (1.0f + __expf(-a));
        }
    }
    __syncthreads();

    // ---- Phase 3: out = xt*wv_w[c]*attn + lambda[c]*ot_1 (pure VALU+store) ----
    // Non-temporal stores: skip L2 write-allocate; output is never re-read.
    const float attn = attnS;
    const int gc    = c0 + ch;
    const float g   = wv_w[gc] * attn;
    const float lam = lambda_t[gc];

    fvec4* ou4 = (fvec4*)(out + base);
    #pragma unroll
    for (int j = 0; j < 8; ++j) {
        const int idx = ch4 + l + j * 32;
        fvec4 r;
        r.x = xr[j].x * g + lam * orr[j].x;
        r.y = xr[j].y * g + lam * orr[j].y;
        r.z = xr[j].z * g + lam * orr[j].z;
        r.w = xr[j].w * g + lam * orr[j].w;
        __builtin_nontemporal_store(r, &ou4[idx]);
    }
}

extern "C" void kernel_launch(void* const* d_in, const int* in_sizes, int n_in,
                              void* d_out, int out_size, void* d_ws, size_t ws_size,
                              hipStream_t stream) {
    const float* xt       = (const float*)d_in[0];
    const float* ot1      = (const float*)d_in[1];
    const float* conv_w   = (const float*)d_in[2];
    const float* wv_w     = (const float*)d_in[3];
    const float* lambda_t = (const float*)d_in[4];
    float* out = (float*)d_out;

    dim3 grid(HEADS, BATCH);   // 16 x 64 = 1024 blocks
    dim3 block(1024);
    mrla_fused_kernel<<<grid, block, 0, stream>>>(xt, ot1, conv_w, wv_w, lambda_t, out);
}

// Round 5
// 64.989 us; speedup vs baseline: 1.0206x; 1.0206x over previous
//
#include <hip/hip_runtime.h>
#include <math.h>

// Problem constants (from reference setup_inputs)
#define BATCH 64
#define CHN   512
#define HW    1024          // 32*32 spatial
#define HEADS 16            // CHN / DIM_PERHEAD
#define DPH   32            // DIM_PERHEAD
#define NTILE (BATCH * HEADS)   // 1024 (b,head) tiles
#define NBLK  (NTILE / 2)       // 512 persistent blocks, 2 tiles each

// Native clang vector type: required by __builtin_nontemporal_store
// (HIP's float4 is a class and is rejected).
typedef float fvec4 __attribute__((ext_vector_type(4)));

// Persistent-ish: 512 blocks x 1024 threads (2 blocks/CU, all resident in
// ONE dispatch round). Each block processes two (b,head) tiles back-to-back;
// tile-1 loads issue in-wave behind tile-0's fire-and-forget nt-stores, so
// the mid-kernel dispatch/drain bubble of the 1024-block version disappears.
// Barrier ordering makes single-buffered poolS/attnS safe across tiles:
// a wave can only write poolS for tile k+1 after passing tile k's second
// barrier, which requires every wave to have finished reading poolS/attnS.
__global__ __launch_bounds__(1024) void mrla_fused_kernel(
    const float* __restrict__ xt,
    const float* __restrict__ ot1,
    const float* __restrict__ conv_w,
    const float* __restrict__ wv_w,
    const float* __restrict__ lambda_t,
    float* __restrict__ out)
{
    const int t  = (int)threadIdx.x; // 0..1023
    const int ch = t >> 5;           // channel within head, 0..31
    const int l  = t & 31;           // lane within channel group

    __shared__ float poolS[DPH + 2]; // pool sums for channels c0-1 .. c0+32
    __shared__ float attnS;

    const int ch4 = ch * (HW / 4);   // this channel's float4 offset
    const int wv  = t >> 6;          // wave id, 0..15
    const int lane = t & 63;

    #pragma unroll
    for (int k = 0; k < 2; ++k) {
        const int tile  = (int)blockIdx.x + k * NBLK;  // 0..1023
        const int b     = tile >> 4;                   // 0..63
        const int headi = tile & 15;                   // 0..15
        const int c0    = headi * DPH;

        const size_t base = ((size_t)b * CHN + c0) * (size_t)HW;
        const fvec4* xt4 = (const fvec4*)(xt + base);

        // ---- Phase 1: load xt tile into registers, per-channel pool sums ----
        fvec4 xr[8];
        float s = 0.0f;
        #pragma unroll
        for (int j = 0; j < 8; ++j) {
            fvec4 v = xt4[ch4 + l + j * 32];
            xr[j] = v;
            s += v.x + v.y + v.z + v.w;
        }
        #pragma unroll
        for (int m = 16; m >= 1; m >>= 1)
            s += __shfl_xor(s, m);
        if (l == 0) poolS[1 + ch] = s;

        // ---- Phase 1b: boundary channels (c0-1 wave 0, c0+32 wave 1) ----
        if (wv < 2) {
            const int gc = (wv == 0) ? (c0 - 1) : (c0 + DPH);
            float bs = 0.0f;
            if (gc >= 0 && gc < CHN) {
                const fvec4* p4 = (const fvec4*)(xt + ((size_t)b * CHN + gc) * (size_t)HW);
                #pragma unroll
                for (int j = 0; j < 4; ++j) {
                    fvec4 v = p4[lane + j * 64];
                    bs += v.x + v.y + v.z + v.w;
                }
            }
            #pragma unroll
            for (int m = 32; m >= 1; m >>= 1)
                bs += __shfl_xor(bs, m);
            if (lane == 0) poolS[(wv == 0) ? 0 : (DPH + 1)] = bs;
        }
        __syncthreads();

        // ---- Phase 2: conv1d(k=3) over channel means, head attn scalar ----
        if (t < DPH) {
            const float inv = 1.0f / (float)HW;
            const float w0 = conv_w[0], w1 = conv_w[1], w2 = conv_w[2];
            float y = (w0 * poolS[t] + w1 * poolS[t + 1] + w2 * poolS[t + 2]) * inv;
            float q = y * y;
            #pragma unroll
            for (int m = 16; m >= 1; m >>= 1)
                q += __shfl_xor(q, m);
            if (t == 0) {
                const float a = q * 0.17677669529663687f;   // / sqrt(32)
                attnS = 1.0f / (1.0f + __expf(-a));
            }
        }
        __syncthreads();

        // ---- Phase 3: out = xt*wv_w[c]*attn + lambda[c]*ot_1 ----
        const float attn = attnS;
        const int gc    = c0 + ch;
        const float g   = wv_w[gc] * attn;
        const float lam = lambda_t[gc];

        const fvec4* o4  = (const fvec4*)(ot1 + base);
        fvec4*       ou4 = (fvec4*)(out + base);
        #pragma unroll
        for (int j = 0; j < 8; ++j) {
            const int idx = ch4 + l + j * 32;
            fvec4 o = o4[idx];
            fvec4 r;
            r.x = xr[j].x * g + lam * o.x;
            r.y = xr[j].y * g + lam * o.y;
            r.z = xr[j].z * g + lam * o.z;
            r.w = xr[j].w * g + lam * o.w;
            __builtin_nontemporal_store(r, &ou4[idx]);
        }
        // No barrier needed here: tile k+1's poolS writes are gated behind
        // its own loads; ordering w.r.t. this tile's poolS readers is
        // guaranteed by the two barriers above (all waves already read them).
    }
}

extern "C" void kernel_launch(void* const* d_in, const int* in_sizes, int n_in,
                              void* d_out, int out_size, void* d_ws, size_t ws_size,
                              hipStream_t stream) {
    const float* xt       = (const float*)d_in[0];
    const float* ot1      = (const float*)d_in[1];
    const float* conv_w   = (const float*)d_in[2];
    const float* wv_w     = (const float*)d_in[3];
    const float* lambda_t = (const float*)d_in[4];
    float* out = (float*)d_out;

    dim3 grid(NBLK);       // 512 blocks, all resident in one round
    dim3 block(1024);
    mrla_fused_kernel<<<grid, block, 0, stream>>>(xt, ot1, conv_w, wv_w, lambda_t, out);
}